// Round 2
// baseline (284.182 us; speedup 1.0000x reference)
//
#include <hip/hip_runtime.h>
#include <hip/hip_bf16.h>

// Binary-weight dense: out[M,N] = scale * x[M,K] @ W[K,N], W = kernel ? +1 : -1
// M = 4*4096 = 16384, K = 1024, N = 1024.
// bf16 MFMA (16x16x32), 128x128x32 block tile, 256 threads (4 waves),
// each wave computes a 64x64 sub-tile as 4x4 MFMA fragments.
// R1: bool kernel dtype is ambiguous (byte vs int32) -> runtime detection kernel
// writes a mode flag to d_ws; GEMM branches block-uniformly on it.

#define M_TOT 16384
#define N_TOT 1024
#define K_TOT 1024
#define BM 128
#define BN 128
#define BK 32
#define BKP 40  // LDS row stride (bf16 elems): 80 B, 16B-multiple (ds_read_b128 ok), breaks pow2 bank stride

typedef __attribute__((ext_vector_type(8))) short bf16x8;
typedef __attribute__((ext_vector_type(4))) float f32x4;

__device__ __forceinline__ unsigned short f2bf(float f) {
    unsigned int u = __builtin_bit_cast(unsigned int, f);
    u += 0x7FFFu + ((u >> 16) & 1u);   // round-to-nearest-even
    return (unsigned short)(u >> 16);
}

// Detect kernel-buffer element width. int32 bools -> words are only 0/1.
// byte-packed bools -> among the first 1024 words (4096 random bools) some
// word is >1 with overwhelming probability.
__global__ void detect_mode(const unsigned int* __restrict__ k32, int* __restrict__ flag) {
    __shared__ int s;
    if (threadIdx.x == 0) s = 0;
    __syncthreads();
    int bad = 0;
    for (int i = threadIdx.x; i < 1024; i += 256)
        if (k32[i] > 1u) bad = 1;
    if (bad) atomicOr(&s, 1);
    __syncthreads();
    if (threadIdx.x == 0) flag[0] = s;   // 1 = byte mode, 0 = int32 mode
}

__global__ __launch_bounds__(256, 2) void binary_dense_gemm(
    const float* __restrict__ x, const void* __restrict__ kern_raw,
    const float* __restrict__ scale_p, float* __restrict__ out,
    const int* __restrict__ mode_p)
{
    __shared__ unsigned short As[BM * BKP];  // As[m][k]
    __shared__ unsigned short Bs[BN * BKP];  // Bs[n][k]  (B tile stored transposed)

    const int tid  = threadIdx.x;
    const int lane = tid & 63;
    const int wave = tid >> 6;
    const int wm = (wave & 1) * 64;   // wave m-offset within block tile
    const int wn = (wave >> 1) * 64;  // wave n-offset within block tile

    const int bx = blockIdx.x & 7;    // 8 n-tiles
    const int by = blockIdx.x >> 3;   // 128 m-tiles
    const int m0 = by * BM;
    const int n0 = bx * BN;

    const float scale = scale_p[0];
    const int byte_mode = mode_p[0];  // block-uniform

    // 16x16x32 bf16 fragment lane decomposition:
    //   A: lane holds A[m = fr][k = fq*8 + j]; B: lane holds B[k = fq*8 + j][n = fr]
    //   C/D: reg j -> row = fq*4 + j, col = fr   (m89/m91-verified)
    const int fr = lane & 15;
    const int fq = lane >> 4;

    f32x4 acc[4][4] = {};

    for (int k0 = 0; k0 < K_TOT; k0 += BK) {
        // ---- stage A: x[m0..m0+128)[k0..k0+32) fp32 -> bf16 ----
        #pragma unroll
        for (int i = 0; i < 4; ++i) {
            int slot = tid + i * 256;
            int row  = slot >> 3;
            int kg   = (slot & 7) << 2;
            const float4 v = *reinterpret_cast<const float4*>(
                x + (size_t)(m0 + row) * K_TOT + k0 + kg);
            ushort4 h;
            h.x = f2bf(v.x); h.y = f2bf(v.y); h.z = f2bf(v.z); h.w = f2bf(v.w);
            *reinterpret_cast<ushort4*>(&As[row * BKP + kg]) = h;
        }
        // ---- stage B: kernel[k0..k0+32)[n0..n0+128) bool -> +-1 bf16, transposed ----
        if (byte_mode) {
            const unsigned char* kern = (const unsigned char*)kern_raw;
            #pragma unroll
            for (int i = 0; i < 4; ++i) {
                int slot = tid + i * 256;
                int nl   = slot & 127;
                int kg   = (slot >> 7) << 2;
                ushort4 h;
                h.x = kern[(size_t)(k0 + kg + 0) * N_TOT + n0 + nl] ? 0x3F80u : 0xBF80u;
                h.y = kern[(size_t)(k0 + kg + 1) * N_TOT + n0 + nl] ? 0x3F80u : 0xBF80u;
                h.z = kern[(size_t)(k0 + kg + 2) * N_TOT + n0 + nl] ? 0x3F80u : 0xBF80u;
                h.w = kern[(size_t)(k0 + kg + 3) * N_TOT + n0 + nl] ? 0x3F80u : 0xBF80u;
                *reinterpret_cast<ushort4*>(&Bs[nl * BKP + kg]) = h;
            }
        } else {
            const int* kern = (const int*)kern_raw;
            #pragma unroll
            for (int i = 0; i < 4; ++i) {
                int slot = tid + i * 256;
                int nl   = slot & 127;
                int kg   = (slot >> 7) << 2;
                ushort4 h;
                h.x = kern[(size_t)(k0 + kg + 0) * N_TOT + n0 + nl] ? 0x3F80u : 0xBF80u;
                h.y = kern[(size_t)(k0 + kg + 1) * N_TOT + n0 + nl] ? 0x3F80u : 0xBF80u;
                h.z = kern[(size_t)(k0 + kg + 2) * N_TOT + n0 + nl] ? 0x3F80u : 0xBF80u;
                h.w = kern[(size_t)(k0 + kg + 3) * N_TOT + n0 + nl] ? 0x3F80u : 0xBF80u;
                *reinterpret_cast<ushort4*>(&Bs[nl * BKP + kg]) = h;
            }
        }
        __syncthreads();

        bf16x8 af[4], bfr[4];
        #pragma unroll
        for (int mi = 0; mi < 4; ++mi)
            af[mi] = *reinterpret_cast<const bf16x8*>(&As[(wm + mi * 16 + fr) * BKP + fq * 8]);
        #pragma unroll
        for (int ni = 0; ni < 4; ++ni)
            bfr[ni] = *reinterpret_cast<const bf16x8*>(&Bs[(wn + ni * 16 + fr) * BKP + fq * 8]);

        #pragma unroll
        for (int mi = 0; mi < 4; ++mi)
            #pragma unroll
            for (int ni = 0; ni < 4; ++ni)
                acc[mi][ni] = __builtin_amdgcn_mfma_f32_16x16x32_bf16(
                    af[mi], bfr[ni], acc[mi][ni], 0, 0, 0);

        __syncthreads();
    }

    // epilogue: C/D layout col = fr, row = fq*4 + j
    #pragma unroll
    for (int mi = 0; mi < 4; ++mi) {
        #pragma unroll
        for (int ni = 0; ni < 4; ++ni) {
            const int col  = n0 + wn + ni * 16 + fr;
            const int rowb = m0 + wm + mi * 16 + fq * 4;
            #pragma unroll
            for (int j = 0; j < 4; ++j)
                out[(size_t)(rowb + j) * N_TOT + col] = scale * acc[mi][ni][j];
        }
    }
}

extern "C" void kernel_launch(void* const* d_in, const int* in_sizes, int n_in,
                              void* d_out, int out_size, void* d_ws, size_t ws_size,
                              hipStream_t stream) {
    const float* x     = (const float*)d_in[0];
    const void*  kern  = d_in[1];
    const float* scale = (const float*)d_in[2];
    float*       out   = (float*)d_out;
    int*         flag  = (int*)d_ws;

    hipLaunchKernelGGL(detect_mode, dim3(1), dim3(256), 0, stream,
                       (const unsigned int*)kern, flag);

    dim3 grid((M_TOT / BM) * (N_TOT / BN));  // 128 * 8 = 1024 blocks
    dim3 block(256);
    hipLaunchKernelGGL(binary_dense_gemm, grid, block, 0, stream,
                       x, kern, scale, out, flag);
}

// Round 4
// 171.028 us; speedup vs baseline: 1.6616x; 1.6616x over previous
//
#include <hip/hip_runtime.h>

// Binary-weight dense: out[M,N] = scale * x[M,K] @ W[K,N], W = kernel ? +1 : -1
// M = 16384, K = 1024, N = 1024.
// R4: kernel bool buffer is int32 (R3 byte-mode failed with the exact
// int32-as-bytes signature; R2 passed via its detector's int32 branch).
// Pipeline:
//   0) detect_mode: flag = 1 if kernel buffer is byte-packed, 0 if int32
//   1) convert_x:  x fp32 -> bf16 into ws[16B .. 32MiB+16B)
//   2) convert_w:  W bools [k][n] -> +-1 bf16 TRANSPOSED [n][k] (dual dtype mode)
//   3) bf16_gemm:  128x128x64 tile, global_load_lds width=16 staging with XOR
//      chunk swizzle, ds_read_b128 fragments, 16x16x32 bf16 MFMA (m97 structure).

#define M_TOT 16384
#define N_TOT 1024
#define K_TOT 1024

typedef __attribute__((ext_vector_type(8))) short bf16x8;
typedef __attribute__((ext_vector_type(4))) float f32x4;

__device__ __forceinline__ unsigned short f2bf(float f) {
    unsigned int u = __builtin_bit_cast(unsigned int, f);
    u += 0x7FFFu + ((u >> 16) & 1u);   // round-to-nearest-even
    return (unsigned short)(u >> 16);
}

// int32 bools -> all words are 0/1; byte-packed bools -> some word >1 among
// the first 1024 words (4096 random bools) with overwhelming probability.
__global__ void detect_mode(const unsigned int* __restrict__ k32, int* __restrict__ flag) {
    __shared__ int s;
    if (threadIdx.x == 0) s = 0;
    __syncthreads();
    int bad = 0;
    for (int i = threadIdx.x; i < 1024; i += 256)
        if (k32[i] > 1u) bad = 1;
    if (bad) atomicOr(&s, 1);
    __syncthreads();
    if (threadIdx.x == 0) flag[0] = s;   // 1 = byte mode, 0 = int32 mode
}

// ---------------- prepass 1: x fp32 -> bf16 ----------------
__global__ __launch_bounds__(256) void convert_x(
    const float4* __restrict__ x, ushort4* __restrict__ xb)
{
    const int S = gridDim.x * blockDim.x;
    int g = blockIdx.x * blockDim.x + threadIdx.x;
    #pragma unroll
    for (int j = 0; j < 4; ++j) {
        int idx = g + j * S;
        float4 v = x[idx];
        ushort4 h;
        h.x = f2bf(v.x); h.y = f2bf(v.y); h.z = f2bf(v.z); h.w = f2bf(v.w);
        xb[idx] = h;
    }
}

// ---------------- prepass 2: W bools [k][n] -> +-1 bf16 [n][k] ----------------
// 64x64 tiles, 256 blocks. Convert to +-1 ushort into LDS [k][n] tile (padded
// stride 72), then write transposed, k-contiguous.
__global__ __launch_bounds__(256) void convert_w(
    const void* __restrict__ w_raw, unsigned short* __restrict__ wt,
    const int* __restrict__ mode_p)
{
    __shared__ unsigned short tile[64 * 72];
    const int tid = threadIdx.x;
    const int k0 = (blockIdx.x & 15) * 64;
    const int n0 = (blockIdx.x >> 4) * 64;
    const int row = tid >> 2;            // k-local
    const int seg = (tid & 3) * 16;      // n-local group of 16

    if (mode_p[0] == 0) {
        // int32 mode: 16 ints = 4 uint4 per thread
        const unsigned int* w = (const unsigned int*)w_raw;
        const uint4* src = reinterpret_cast<const uint4*>(
            w + (size_t)(k0 + row) * N_TOT + n0 + seg);
        #pragma unroll
        for (int q = 0; q < 4; ++q) {
            uint4 v = src[q];
            ushort4 h;
            h.x = v.x ? 0x3F80u : 0xBF80u;
            h.y = v.y ? 0x3F80u : 0xBF80u;
            h.z = v.z ? 0x3F80u : 0xBF80u;
            h.w = v.w ? 0x3F80u : 0xBF80u;
            *reinterpret_cast<ushort4*>(&tile[row * 72 + seg + q * 4]) = h;
        }
    } else {
        // byte mode: 16 bytes = 1 uint4 per thread
        const unsigned char* w = (const unsigned char*)w_raw;
        uint4 v = *reinterpret_cast<const uint4*>(
            w + (size_t)(k0 + row) * N_TOT + n0 + seg);
        unsigned char b[16];
        *reinterpret_cast<uint4*>(b) = v;
        #pragma unroll
        for (int q = 0; q < 4; ++q) {
            ushort4 h;
            h.x = b[q * 4 + 0] ? 0x3F80u : 0xBF80u;
            h.y = b[q * 4 + 1] ? 0x3F80u : 0xBF80u;
            h.z = b[q * 4 + 2] ? 0x3F80u : 0xBF80u;
            h.w = b[q * 4 + 3] ? 0x3F80u : 0xBF80u;
            *reinterpret_cast<ushort4*>(&tile[row * 72 + seg + q * 4]) = h;
        }
    }
    __syncthreads();
    {   // write-out: thread -> (n, 16 consecutive k)
        int n = tid >> 2, kseg = (tid & 3) * 16;
        ushort4 o[4];
        #pragma unroll
        for (int j = 0; j < 16; ++j)
            ((unsigned short*)o)[j] = tile[(kseg + j) * 72 + n];
        ushort4* dst = reinterpret_cast<ushort4*>(wt + (size_t)(n0 + n) * K_TOT + k0 + kseg);
        dst[0] = o[0]; dst[1] = o[1]; dst[2] = o[2]; dst[3] = o[3];
    }
}

// ---------------- main GEMM: out = scale * A(bf16) @ BT(bf16)^T ----------------
__global__ __launch_bounds__(256) void bf16_gemm(
    const unsigned short* __restrict__ A,    // [M][K] bf16
    const unsigned short* __restrict__ BT,   // [N][K] bf16 (pre-transposed W)
    const float* __restrict__ scale_p, float* __restrict__ out)
{
    // Unpadded LDS (global_load_lds requires base + lane*16 contiguity, m104).
    // Bank balance via XOR chunk swizzle: LDS[r][c] holds global chunk c^(r&7).
    __shared__ unsigned short As[128 * 64];  // 16 KiB
    __shared__ unsigned short Bs[128 * 64];

    const int tid  = threadIdx.x;
    const int lane = tid & 63;
    const int wave = tid >> 6;
    const int wm = (wave & 1) * 64;
    const int wn = (wave >> 1) * 64;
    const int bx = blockIdx.x & 7;    // 8 n-tiles
    const int by = blockIdx.x >> 3;   // 128 m-tiles
    const int m0 = by * 128, n0 = bx * 128;
    const int fr = lane & 15, fq = lane >> 4;
    const float scale = scale_p[0];

    // staging: issue q of wave w covers LDS rows w*32+q*8 .. +8; lane i lands at
    // row w*32+q*8+(i>>3), LDS chunk i&7; source global k-chunk = (i&7)^(i>>3).
    const int srow = wave * 32 + (lane >> 3);
    const int skch = (lane & 7) ^ (lane >> 3);

    f32x4 acc[4][4] = {};

    for (int k0 = 0; k0 < K_TOT; k0 += 64) {
        #pragma unroll
        for (int q = 0; q < 4; ++q) {
            const unsigned short* g = A + (size_t)(m0 + srow + q * 8) * K_TOT + k0 + skch * 8;
            __builtin_amdgcn_global_load_lds(
                (const __attribute__((address_space(1))) void*)g,
                (__attribute__((address_space(3))) void*)&As[wave * 2048 + q * 512],
                16, 0, 0);
        }
        #pragma unroll
        for (int q = 0; q < 4; ++q) {
            const unsigned short* g = BT + (size_t)(n0 + srow + q * 8) * K_TOT + k0 + skch * 8;
            __builtin_amdgcn_global_load_lds(
                (const __attribute__((address_space(1))) void*)g,
                (__attribute__((address_space(3))) void*)&Bs[wave * 2048 + q * 512],
                16, 0, 0);
        }
        __syncthreads();

        #pragma unroll
        for (int ks = 0; ks < 2; ++ks) {
            bf16x8 af[4], bfr[4];
            #pragma unroll
            for (int mi = 0; mi < 4; ++mi) {
                int r  = wm + mi * 16 + fr;
                int ch = (ks * 4 + fq) ^ (r & 7);
                af[mi] = *reinterpret_cast<const bf16x8*>(&As[r * 64 + ch * 8]);
            }
            #pragma unroll
            for (int ni = 0; ni < 4; ++ni) {
                int r  = wn + ni * 16 + fr;
                int ch = (ks * 4 + fq) ^ (r & 7);
                bfr[ni] = *reinterpret_cast<const bf16x8*>(&Bs[r * 64 + ch * 8]);
            }
            #pragma unroll
            for (int mi = 0; mi < 4; ++mi)
                #pragma unroll
                for (int ni = 0; ni < 4; ++ni)
                    acc[mi][ni] = __builtin_amdgcn_mfma_f32_16x16x32_bf16(
                        af[mi], bfr[ni], acc[mi][ni], 0, 0, 0);
        }
        __syncthreads();
    }

    // epilogue: C/D layout col = fr, row = fq*4 + j  (m89/m91-verified)
    #pragma unroll
    for (int mi = 0; mi < 4; ++mi) {
        #pragma unroll
        for (int ni = 0; ni < 4; ++ni) {
            const int col  = n0 + wn + ni * 16 + fr;
            const int rowb = m0 + wm + mi * 16 + fq * 4;
            #pragma unroll
            for (int j = 0; j < 4; ++j)
                out[(size_t)(rowb + j) * N_TOT + col] = scale * acc[mi][ni][j];
        }
    }
}

// ---------------- fallback (ws too small): fused kernel, int32 weights ----------------
#define BKP 40
__global__ __launch_bounds__(256, 2) void binary_dense_gemm(
    const float* __restrict__ x, const int* __restrict__ kern,
    const float* __restrict__ scale_p, float* __restrict__ out)
{
    __shared__ unsigned short Asf[128 * BKP];
    __shared__ unsigned short Bsf[128 * BKP];
    const int tid = threadIdx.x, lane = tid & 63, wave = tid >> 6;
    const int wm = (wave & 1) * 64, wn = (wave >> 1) * 64;
    const int bx = blockIdx.x & 7, by = blockIdx.x >> 3;
    const int m0 = by * 128, n0 = bx * 128;
    const float scale = scale_p[0];
    const int fr = lane & 15, fq = lane >> 4;
    f32x4 acc[4][4] = {};
    for (int k0 = 0; k0 < K_TOT; k0 += 32) {
        #pragma unroll
        for (int i = 0; i < 4; ++i) {
            int slot = tid + i * 256, row = slot >> 3, kg = (slot & 7) << 2;
            const float4 v = *reinterpret_cast<const float4*>(x + (size_t)(m0 + row) * K_TOT + k0 + kg);
            ushort4 h;
            h.x = f2bf(v.x); h.y = f2bf(v.y); h.z = f2bf(v.z); h.w = f2bf(v.w);
            *reinterpret_cast<ushort4*>(&Asf[row * BKP + kg]) = h;
        }
        #pragma unroll
        for (int i = 0; i < 4; ++i) {
            int slot = tid + i * 256, nl = slot & 127, kg = (slot >> 7) << 2;
            ushort4 h;
            h.x = kern[(size_t)(k0 + kg + 0) * N_TOT + n0 + nl] ? 0x3F80u : 0xBF80u;
            h.y = kern[(size_t)(k0 + kg + 1) * N_TOT + n0 + nl] ? 0x3F80u : 0xBF80u;
            h.z = kern[(size_t)(k0 + kg + 2) * N_TOT + n0 + nl] ? 0x3F80u : 0xBF80u;
            h.w = kern[(size_t)(k0 + kg + 3) * N_TOT + n0 + nl] ? 0x3F80u : 0xBF80u;
            *reinterpret_cast<ushort4*>(&Bsf[nl * BKP + kg]) = h;
        }
        __syncthreads();
        bf16x8 af[4], bfr[4];
        #pragma unroll
        for (int mi = 0; mi < 4; ++mi)
            af[mi] = *reinterpret_cast<const bf16x8*>(&Asf[(wm + mi * 16 + fr) * BKP + fq * 8]);
        #pragma unroll
        for (int ni = 0; ni < 4; ++ni)
            bfr[ni] = *reinterpret_cast<const bf16x8*>(&Bsf[(wn + ni * 16 + fr) * BKP + fq * 8]);
        #pragma unroll
        for (int mi = 0; mi < 4; ++mi)
            #pragma unroll
            for (int ni = 0; ni < 4; ++ni)
                acc[mi][ni] = __builtin_amdgcn_mfma_f32_16x16x32_bf16(af[mi], bfr[ni], acc[mi][ni], 0, 0, 0);
        __syncthreads();
    }
    #pragma unroll
    for (int mi = 0; mi < 4; ++mi)
        #pragma unroll
        for (int ni = 0; ni < 4; ++ni) {
            const int col = n0 + wn + ni * 16 + fr;
            const int rowb = m0 + wm + mi * 16 + fq * 4;
            #pragma unroll
            for (int j = 0; j < 4; ++j)
                out[(size_t)(rowb + j) * N_TOT + col] = scale * acc[mi][ni][j];
        }
}

extern "C" void kernel_launch(void* const* d_in, const int* in_sizes, int n_in,
                              void* d_out, int out_size, void* d_ws, size_t ws_size,
                              hipStream_t stream) {
    const float* x     = (const float*)d_in[0];
    const void*  kern  = d_in[1];
    const float* scale = (const float*)d_in[2];
    float*       out   = (float*)d_out;

    const size_t xb_bytes = (size_t)M_TOT * K_TOT * 2;           // 32 MiB
    const size_t wt_bytes = (size_t)N_TOT * K_TOT * 2;           //  2 MiB
    const size_t flag_off = 256;                                  // keep ws 16B-aligned
    if (ws_size >= flag_off + xb_bytes + wt_bytes) {
        int*            flag = (int*)d_ws;
        unsigned short* xb   = (unsigned short*)((char*)d_ws + flag_off);
        unsigned short* wt   = (unsigned short*)((char*)d_ws + flag_off + xb_bytes);
        hipLaunchKernelGGL(detect_mode, dim3(1), dim3(256), 0, stream,
                           (const unsigned int*)kern, flag);
        hipLaunchKernelGGL(convert_x, dim3(4096), dim3(256), 0, stream,
                           (const float4*)x, (ushort4*)xb);
        hipLaunchKernelGGL(convert_w, dim3(256), dim3(256), 0, stream, kern, wt, flag);
        hipLaunchKernelGGL(bf16_gemm, dim3(1024), dim3(256), 0, stream,
                           xb, wt, scale, out);
    } else {
        hipLaunchKernelGGL(binary_dense_gemm, dim3(1024), dim3(256), 0, stream,
                           x, (const int*)kern, scale, out);
    }
}

// Round 5
// 161.145 us; speedup vs baseline: 1.7635x; 1.0613x over previous
//
#include <hip/hip_runtime.h>

// Binary-weight dense: out[M,N] = scale * x[M,K] @ W[K,N], W = kernel ? +1 : -1
// M = 16384, K = 1024, N = 1024.
// R5: R4 pipeline + XCD-aware block swizzle in the GEMM. R4's FETCH was 133 MB
// (4x the 34 MB unique input): the 8 n-tile blocks sharing an A m-strip were
// consecutive blockIdx -> spread round-robin over all 8 XCDs, each XCD L2
// filling its own strip copy. New mapping puts all 8 same-strip blocks on one
// XCD (b % 8 invariant) within a 64-block dispatch window.
// Pipeline: detect_mode -> convert_x (fp32->bf16) -> convert_w (bool->+-1 bf16,
// transposed [n][k]) -> bf16_gemm (128x128x64, global_load_lds w=16, XOR chunk
// swizzle, 16x16x32 bf16 MFMA).

#define M_TOT 16384
#define N_TOT 1024
#define K_TOT 1024

typedef __attribute__((ext_vector_type(8))) short bf16x8;
typedef __attribute__((ext_vector_type(4))) float f32x4;

__device__ __forceinline__ unsigned short f2bf(float f) {
    unsigned int u = __builtin_bit_cast(unsigned int, f);
    u += 0x7FFFu + ((u >> 16) & 1u);   // round-to-nearest-even
    return (unsigned short)(u >> 16);
}

// int32 bools -> all words are 0/1; byte-packed bools -> some word >1 among
// the first 1024 words with overwhelming probability.
__global__ void detect_mode(const unsigned int* __restrict__ k32, int* __restrict__ flag) {
    __shared__ int s;
    if (threadIdx.x == 0) s = 0;
    __syncthreads();
    int bad = 0;
    for (int i = threadIdx.x; i < 1024; i += 256)
        if (k32[i] > 1u) bad = 1;
    if (bad) atomicOr(&s, 1);
    __syncthreads();
    if (threadIdx.x == 0) flag[0] = s;   // 1 = byte mode, 0 = int32 mode
}

// ---------------- prepass 1: x fp32 -> bf16 ----------------
__global__ __launch_bounds__(256) void convert_x(
    const float4* __restrict__ x, ushort4* __restrict__ xb)
{
    const int S = gridDim.x * blockDim.x;
    int g = blockIdx.x * blockDim.x + threadIdx.x;
    #pragma unroll
    for (int j = 0; j < 4; ++j) {
        int idx = g + j * S;
        float4 v = x[idx];
        ushort4 h;
        h.x = f2bf(v.x); h.y = f2bf(v.y); h.z = f2bf(v.z); h.w = f2bf(v.w);
        xb[idx] = h;
    }
}

// ---------------- prepass 2: W bools [k][n] -> +-1 bf16 [n][k] ----------------
__global__ __launch_bounds__(256) void convert_w(
    const void* __restrict__ w_raw, unsigned short* __restrict__ wt,
    const int* __restrict__ mode_p)
{
    __shared__ unsigned short tile[64 * 72];
    const int tid = threadIdx.x;
    const int k0 = (blockIdx.x & 15) * 64;
    const int n0 = (blockIdx.x >> 4) * 64;
    const int row = tid >> 2;            // k-local
    const int seg = (tid & 3) * 16;      // n-local group of 16

    if (mode_p[0] == 0) {
        // int32 mode: 16 ints = 4 uint4 per thread
        const unsigned int* w = (const unsigned int*)w_raw;
        const uint4* src = reinterpret_cast<const uint4*>(
            w + (size_t)(k0 + row) * N_TOT + n0 + seg);
        #pragma unroll
        for (int q = 0; q < 4; ++q) {
            uint4 v = src[q];
            ushort4 h;
            h.x = v.x ? 0x3F80u : 0xBF80u;
            h.y = v.y ? 0x3F80u : 0xBF80u;
            h.z = v.z ? 0x3F80u : 0xBF80u;
            h.w = v.w ? 0x3F80u : 0xBF80u;
            *reinterpret_cast<ushort4*>(&tile[row * 72 + seg + q * 4]) = h;
        }
    } else {
        // byte mode: 16 bytes = 1 uint4 per thread
        const unsigned char* w = (const unsigned char*)w_raw;
        uint4 v = *reinterpret_cast<const uint4*>(
            w + (size_t)(k0 + row) * N_TOT + n0 + seg);
        unsigned char b[16];
        *reinterpret_cast<uint4*>(b) = v;
        #pragma unroll
        for (int q = 0; q < 4; ++q) {
            ushort4 h;
            h.x = b[q * 4 + 0] ? 0x3F80u : 0xBF80u;
            h.y = b[q * 4 + 1] ? 0x3F80u : 0xBF80u;
            h.z = b[q * 4 + 2] ? 0x3F80u : 0xBF80u;
            h.w = b[q * 4 + 3] ? 0x3F80u : 0xBF80u;
            *reinterpret_cast<ushort4*>(&tile[row * 72 + seg + q * 4]) = h;
        }
    }
    __syncthreads();
    {   // write-out: thread -> (n, 16 consecutive k)
        int n = tid >> 2, kseg = (tid & 3) * 16;
        ushort4 o[4];
        #pragma unroll
        for (int j = 0; j < 16; ++j)
            ((unsigned short*)o)[j] = tile[(kseg + j) * 72 + n];
        ushort4* dst = reinterpret_cast<ushort4*>(wt + (size_t)(n0 + n) * K_TOT + k0 + kseg);
        dst[0] = o[0]; dst[1] = o[1]; dst[2] = o[2]; dst[3] = o[3];
    }
}

// ---------------- main GEMM: out = scale * A(bf16) @ BT(bf16)^T ----------------
__global__ __launch_bounds__(256) void bf16_gemm(
    const unsigned short* __restrict__ A,    // [M][K] bf16
    const unsigned short* __restrict__ BT,   // [N][K] bf16 (pre-transposed W)
    const float* __restrict__ scale_p, float* __restrict__ out)
{
    // Unpadded LDS (global_load_lds needs base + lane*16 contiguity, m104).
    // Bank balance via XOR chunk swizzle: LDS[r][c] holds global chunk c^(r&7).
    __shared__ unsigned short As[128 * 64];  // 16 KiB
    __shared__ unsigned short Bs[128 * 64];

    const int tid  = threadIdx.x;
    const int lane = tid & 63;
    const int wave = tid >> 6;
    const int wm = (wave & 1) * 64;
    const int wn = (wave >> 1) * 64;

    // XCD-aware swizzle: all 8 blocks sharing an A m-strip get the same
    // (blockIdx % 8) -> same XCD under round-robin dispatch, and sit within
    // one 64-block dispatch window (co-resident) -> one L2 fill per strip.
    const int j  = blockIdx.x & 7;
    const int s  = blockIdx.x >> 3;
    const int by = ((s >> 3) << 3) | j;   // 0..127
    const int bx = s & 7;                 // 0..7
    const int m0 = by * 128, n0 = bx * 128;

    const int fr = lane & 15, fq = lane >> 4;
    const float scale = scale_p[0];

    // staging: issue q of wave w covers LDS rows w*32+q*8 .. +8; lane i lands at
    // row w*32+q*8+(i>>3), LDS chunk i&7; source global k-chunk = (i&7)^(i>>3).
    const int srow = wave * 32 + (lane >> 3);
    const int skch = (lane & 7) ^ (lane >> 3);

    f32x4 acc[4][4] = {};

    for (int k0 = 0; k0 < K_TOT; k0 += 64) {
        #pragma unroll
        for (int q = 0; q < 4; ++q) {
            const unsigned short* g = A + (size_t)(m0 + srow + q * 8) * K_TOT + k0 + skch * 8;
            __builtin_amdgcn_global_load_lds(
                (const __attribute__((address_space(1))) void*)g,
                (__attribute__((address_space(3))) void*)&As[wave * 2048 + q * 512],
                16, 0, 0);
        }
        #pragma unroll
        for (int q = 0; q < 4; ++q) {
            const unsigned short* g = BT + (size_t)(n0 + srow + q * 8) * K_TOT + k0 + skch * 8;
            __builtin_amdgcn_global_load_lds(
                (const __attribute__((address_space(1))) void*)g,
                (__attribute__((address_space(3))) void*)&Bs[wave * 2048 + q * 512],
                16, 0, 0);
        }
        __syncthreads();

        #pragma unroll
        for (int ks = 0; ks < 2; ++ks) {
            bf16x8 af[4], bfr[4];
            #pragma unroll
            for (int mi = 0; mi < 4; ++mi) {
                int r  = wm + mi * 16 + fr;
                int ch = (ks * 4 + fq) ^ (r & 7);
                af[mi] = *reinterpret_cast<const bf16x8*>(&As[r * 64 + ch * 8]);
            }
            #pragma unroll
            for (int ni = 0; ni < 4; ++ni) {
                int r  = wn + ni * 16 + fr;
                int ch = (ks * 4 + fq) ^ (r & 7);
                bfr[ni] = *reinterpret_cast<const bf16x8*>(&Bs[r * 64 + ch * 8]);
            }
            #pragma unroll
            for (int mi = 0; mi < 4; ++mi)
                #pragma unroll
                for (int ni = 0; ni < 4; ++ni)
                    acc[mi][ni] = __builtin_amdgcn_mfma_f32_16x16x32_bf16(
                        af[mi], bfr[ni], acc[mi][ni], 0, 0, 0);
        }
        __syncthreads();
    }

    // epilogue: C/D layout col = fr, row = fq*4 + j  (m89/m91-verified)
    #pragma unroll
    for (int mi = 0; mi < 4; ++mi) {
        #pragma unroll
        for (int ni = 0; ni < 4; ++ni) {
            const int col  = n0 + wn + ni * 16 + fr;
            const int rowb = m0 + wm + mi * 16 + fq * 4;
            #pragma unroll
            for (int jj = 0; jj < 4; ++jj)
                out[(size_t)(rowb + jj) * N_TOT + col] = scale * acc[mi][ni][jj];
        }
    }
}

// ---------------- fallback (ws too small): fused kernel, int32 weights ----------------
#define BKP 40
__global__ __launch_bounds__(256, 2) void binary_dense_gemm(
    const float* __restrict__ x, const int* __restrict__ kern,
    const float* __restrict__ scale_p, float* __restrict__ out)
{
    __shared__ unsigned short Asf[128 * BKP];
    __shared__ unsigned short Bsf[128 * BKP];
    const int tid = threadIdx.x, lane = tid & 63, wave = tid >> 6;
    const int wm = (wave & 1) * 64, wn = (wave >> 1) * 64;
    const int bx = blockIdx.x & 7, by = blockIdx.x >> 3;
    const int m0 = by * 128, n0 = bx * 128;
    const float scale = scale_p[0];
    const int fr = lane & 15, fq = lane >> 4;
    f32x4 acc[4][4] = {};
    for (int k0 = 0; k0 < K_TOT; k0 += 32) {
        #pragma unroll
        for (int i = 0; i < 4; ++i) {
            int slot = tid + i * 256, row = slot >> 3, kg = (slot & 7) << 2;
            const float4 v = *reinterpret_cast<const float4*>(x + (size_t)(m0 + row) * K_TOT + k0 + kg);
            ushort4 h;
            h.x = f2bf(v.x); h.y = f2bf(v.y); h.z = f2bf(v.z); h.w = f2bf(v.w);
            *reinterpret_cast<ushort4*>(&Asf[row * BKP + kg]) = h;
        }
        #pragma unroll
        for (int i = 0; i < 4; ++i) {
            int slot = tid + i * 256, nl = slot & 127, kg = (slot >> 7) << 2;
            ushort4 h;
            h.x = kern[(size_t)(k0 + kg + 0) * N_TOT + n0 + nl] ? 0x3F80u : 0xBF80u;
            h.y = kern[(size_t)(k0 + kg + 1) * N_TOT + n0 + nl] ? 0x3F80u : 0xBF80u;
            h.z = kern[(size_t)(k0 + kg + 2) * N_TOT + n0 + nl] ? 0x3F80u : 0xBF80u;
            h.w = kern[(size_t)(k0 + kg + 3) * N_TOT + n0 + nl] ? 0x3F80u : 0xBF80u;
            *reinterpret_cast<ushort4*>(&Bsf[nl * BKP + kg]) = h;
        }
        __syncthreads();
        bf16x8 af[4], bfr[4];
        #pragma unroll
        for (int mi = 0; mi < 4; ++mi)
            af[mi] = *reinterpret_cast<const bf16x8*>(&Asf[(wm + mi * 16 + fr) * BKP + fq * 8]);
        #pragma unroll
        for (int ni = 0; ni < 4; ++ni)
            bfr[ni] = *reinterpret_cast<const bf16x8*>(&Bsf[(wn + ni * 16 + fr) * BKP + fq * 8]);
        #pragma unroll
        for (int mi = 0; mi < 4; ++mi)
            #pragma unroll
            for (int ni = 0; ni < 4; ++ni)
                acc[mi][ni] = __builtin_amdgcn_mfma_f32_16x16x32_bf16(af[mi], bfr[ni], acc[mi][ni], 0, 0, 0);
        __syncthreads();
    }
    #pragma unroll
    for (int mi = 0; mi < 4; ++mi)
        #pragma unroll
        for (int ni = 0; ni < 4; ++ni) {
            const int col = n0 + wn + ni * 16 + fr;
            const int rowb = m0 + wm + mi * 16 + fq * 4;
            #pragma unroll
            for (int jj = 0; jj < 4; ++jj)
                out[(size_t)(rowb + jj) * N_TOT + col] = scale * acc[mi][ni][jj];
        }
}

extern "C" void kernel_launch(void* const* d_in, const int* in_sizes, int n_in,
                              void* d_out, int out_size, void* d_ws, size_t ws_size,
                              hipStream_t stream) {
    const float* x     = (const float*)d_in[0];
    const void*  kern  = d_in[1];
    const float* scale = (const float*)d_in[2];
    float*       out   = (float*)d_out;

    const size_t xb_bytes = (size_t)M_TOT * K_TOT * 2;           // 32 MiB
    const size_t wt_bytes = (size_t)N_TOT * K_TOT * 2;           //  2 MiB
    const size_t flag_off = 256;                                  // keep ws 16B-aligned
    if (ws_size >= flag_off + xb_bytes + wt_bytes) {
        int*            flag = (int*)d_ws;
        unsigned short* xb   = (unsigned short*)((char*)d_ws + flag_off);
        unsigned short* wt   = (unsigned short*)((char*)d_ws + flag_off + xb_bytes);
        hipLaunchKernelGGL(detect_mode, dim3(1), dim3(256), 0, stream,
                           (const unsigned int*)kern, flag);
        hipLaunchKernelGGL(convert_w, dim3(256), dim3(256), 0, stream, kern, wt, flag);
        hipLaunchKernelGGL(convert_x, dim3(4096), dim3(256), 0, stream,
                           (const float4*)x, (ushort4*)xb);
        hipLaunchKernelGGL(bf16_gemm, dim3(1024), dim3(256), 0, stream,
                           xb, wt, scale, out);
    } else {
        hipLaunchKernelGGL(binary_dense_gemm, dim3(1024), dim3(256), 0, stream,
                           x, (const int*)kern, scale, out);
    }
}